// Round 1
// baseline (41.701 us; speedup 1.0000x reference)
//
#include <hip/hip_runtime.h>

#define NP 64          // z_vals per ray
#define NS 64          // N_importance (fixed by problem)
#define M  62          // w_mid count = NP - 2
#define NB 63          // bins (z_mid) count = NP - 1
#define RPB 4          // rays per block (one wave each)

__global__ __launch_bounds__(256) void nerf_fine_kernel(
    const float* __restrict__ rays_o,
    const float* __restrict__ rays_d,
    const float* __restrict__ weights,
    const float* __restrict__ z_vals,
    float* __restrict__ pts,        // [N,128,3]
    float* __restrict__ z_all_out,  // [N,128]
    int N)
{
    __shared__ float s_bins[RPB][NB];
    __shared__ float s_cdf[RPB][NB];
    __shared__ float s_zval[RPB][NP];
    __shared__ float s_zsamp[RPB][NS];
    __shared__ float s_zall[RPB][NP + NS];

    const int lane = threadIdx.x & 63;
    const int w    = threadIdx.x >> 6;                 // wave slot in block
    const int ray  = blockIdx.x * RPB + w;
    if (ray >= N) return;                              // N % RPB == 0 here; guard is moot

    // ---- load (coalesced: 64 lanes x 4B contiguous per ray) ----
    const float zv = z_vals[(size_t)ray * NP + lane];
    const float wt = weights[(size_t)ray * NP + lane];
    s_zval[w][lane] = zv;

    // z_mid[l] = 0.5*(z[l] + z[l+1]), l in [0,63)
    const float znext = __shfl_down(zv, 1);
    if (lane < NB) s_bins[w][lane] = 0.5f * (zv + znext);

    // w_mid[l] = weights[l+1] + EPS_W, l in [0,62)
    const float wnext = __shfl_down(wt, 1);
    float v = (lane < M) ? (wnext + 1e-5f) : 0.0f;

    // wave inclusive scan (6 steps)
    #pragma unroll
    for (int off = 1; off < 64; off <<= 1) {
        float t = __shfl_up(v, off);
        if (lane >= off) v += t;
    }
    const float total = __shfl(v, 63);                 // lanes 62,63 contributed 0

    // cdf[0] = 0; cdf[k] = scan[k-1]/total, k = 1..62  (cdf[62] == 1 exactly)
    if (lane == 63) s_cdf[w][0] = 0.0f;
    if (lane < M)   s_cdf[w][lane + 1] = v / total;
    __syncthreads();

    // ---- inverse-CDF sample: u = lane/63, searchsorted side='right' over cdf[0..61] ----
    const float u = (float)lane / 63.0f;
    int lo = 0, hi = M;
    while (lo < hi) {
        int mid = (lo + hi) >> 1;
        if (s_cdf[w][mid] <= u) lo = mid + 1; else hi = mid;
    }
    const int above = lo;                              // in [1, 62]
    const int below = above - 1;
    const float cb = s_cdf[w][below], ca = s_cdf[w][above];
    const float bb = s_bins[w][below], ba = s_bins[w][above];
    float denom = ca - cb;
    if (denom < 1e-5f) denom = 1.0f;
    const float t  = (u - cb) / denom;
    const float zs = bb + t * (ba - bb);
    s_zsamp[w][lane] = zs;                             // sorted (u increasing, CDF monotone)
    __syncthreads();

    // ---- merge two sorted 64-arrays via ranks (stable: z_vals before equal samples) ----
    {   // pos(zv) = lane + #{ zsamp < zv }
        int l2 = 0, h2 = NS;
        while (l2 < h2) { int mid = (l2 + h2) >> 1; if (s_zsamp[w][mid] < zv) l2 = mid + 1; else h2 = mid; }
        s_zall[w][lane + l2] = zv;
    }
    {   // pos(zs) = lane + #{ zval <= zs }
        int l2 = 0, h2 = NP;
        while (l2 < h2) { int mid = (l2 + h2) >> 1; if (s_zval[w][mid] <= zs) l2 = mid + 1; else h2 = mid; }
        s_zall[w][lane + l2] = zs;
    }
    __syncthreads();

    // ---- outputs ----
    // z_all: [N,128], two coalesced stores
    z_all_out[(size_t)ray * 128 + lane]      = s_zall[w][lane];
    z_all_out[(size_t)ray * 128 + 64 + lane] = s_zall[w][lane + 64];

    // pts: [N,128,3] -> 384 contiguous floats per ray; lane writes idx = m*64+lane
    const float rd0 = rays_d[(size_t)ray * 3 + 0];
    const float rd1 = rays_d[(size_t)ray * 3 + 1];
    const float rd2 = rays_d[(size_t)ray * 3 + 2];
    const float ro0 = rays_o[(size_t)ray * 3 + 0];
    const float ro1 = rays_o[(size_t)ray * 3 + 1];
    const float ro2 = rays_o[(size_t)ray * 3 + 2];

    #pragma unroll
    for (int m2 = 0; m2 < 6; ++m2) {
        const int idx = m2 * 64 + lane;                // 0..383
        const int k   = idx / 3;                       // constant divide -> mul/shift
        const int c   = idx - 3 * k;
        const float rdc = (c == 0) ? rd0 : ((c == 1) ? rd1 : rd2);
        const float roc = (c == 0) ? ro0 : ((c == 1) ? ro1 : ro2);
        pts[(size_t)ray * 384 + idx] = fmaf(s_zall[w][k], rdc, roc);
    }
}

extern "C" void kernel_launch(void* const* d_in, const int* in_sizes, int n_in,
                              void* d_out, int out_size, void* d_ws, size_t ws_size,
                              hipStream_t stream) {
    const float* rays_o  = (const float*)d_in[0];
    const float* rays_d  = (const float*)d_in[1];
    const float* weights = (const float*)d_in[2];
    const float* z_vals  = (const float*)d_in[3];
    // d_in[4] = N_importance (== 64, fixed by problem shape)

    const int N = in_sizes[2] / NP;                    // weights is [N, 64]
    float* pts   = (float*)d_out;                      // [N,128,3]
    float* z_all = (float*)d_out + (size_t)N * 128 * 3;

    const int blocks = (N + RPB - 1) / RPB;
    nerf_fine_kernel<<<blocks, 256, 0, stream>>>(rays_o, rays_d, weights, z_vals,
                                                 pts, z_all, N);
}